// Round 1
// baseline (323.730 us; speedup 1.0000x reference)
//
#include <hip/hip_runtime.h>
#include <hip/hip_bf16.h>

#define BB 512
#define SS 1024
#define DIN 64
#define HH 64
#define SD4 4
#define CH 64     // scan chunk length
#define LB 64     // scan lookback (0.925^64 = 6.8e-3 decay of init error)

typedef __attribute__((ext_vector_type(8))) short s8v;   // 8 bf16 (4 VGPRs)
typedef __attribute__((ext_vector_type(4))) float f4v;   // MFMA accumulator

#define MFMA_BF16(a, b, c) __builtin_amdgcn_mfma_f32_16x16x32_bf16((a), (b), (c), 0, 0, 0)

// DPP cross-lane move in the VALU pipe. ctrl: 0x00-0xFF quad_perm; 0x120+N row_ror:N.
template <int CTRL>
__device__ __forceinline__ float dppf(float v) {
    return __int_as_float(__builtin_amdgcn_mov_dpp(__float_as_int(v), CTRL, 0xF, 0xF, false));
}

__device__ __forceinline__ float rcp_fast(float x) {
    return __builtin_amdgcn_rcpf(x);   // v_rcp_f32: 1 instr, ~1 ulp
}
// HW packed f32->bf16 (RNE), 2 elements per instruction.
__device__ __forceinline__ unsigned int cvt_pk(float lo, float hi) {
    unsigned int r;
    asm("v_cvt_pk_bf16_f32 %0, %1, %2" : "=v"(r) : "v"(lo), "v"(hi));
    return r;
}
__device__ __forceinline__ float bf2f(unsigned short u) {
    return __uint_as_float(((unsigned int)u) << 16);
}
__device__ __forceinline__ float sigmoid_f(float x) {
    return 1.0f / (1.0f + __expf(-x));
}
__device__ __forceinline__ float tanh_fast(float x) {
    return fmaf(-2.0f, rcp_fast(__expf(2.0f * x) + 1.0f), 1.0f);
}
__device__ __forceinline__ float gelu_fast(float x) {
    // tanh-form GELU as x*sigmoid(-z)
    float x2 = x * x;
    float z = x * fmaf(x2, -0.0713548162f, -1.5957691216f);
    return x * rcp_fast(1.0f + __expf(z));
}
__device__ __forceinline__ s8v cvt8(const float* __restrict__ p) {
    const float4* q4 = (const float4*)p;
    float4 a = q4[0], b = q4[1];
    union { s8v s; unsigned int u[4]; } r;
    r.u[0] = cvt_pk(a.x, a.y); r.u[1] = cvt_pk(a.z, a.w);
    r.u[2] = cvt_pk(b.x, b.y); r.u[3] = cvt_pk(b.z, b.w);
    return r.s;
}

// ---------------------------------------------------------------------------
// Phase 1 (MFMA), per 16-token tile:
//   h = GELU(LN(x @ W1^T + b1)); pre = h @ Wc1[:,4:]^T + bc1; bx = h @ Wi^T + bi
// R6 structure:
//  - A-fragments loaded DIRECTLY from global (lane (c,q) owns x[tok0+c][q*8..])
//    one tile ahead; no xs LDS stage, conversions via v_cvt_pk_bf16_f32.
//  - Biases folded into MFMA C-in.
//  - Wc1 B-fragments live in block-shared LDS (bf16, row stride 72 shorts ->
//    bank-floor reads), freeing 32 persistent VGPRs.
//  - Software pipeline: iter t issues H(t) ds_reads, then runs GEMM1(t+1)+LN+
//    GELU (pure VALU, no DS ops) to hide the hb round-trip, then GEMM2(t),
//    stores(t), and finally ds_writes h(t+1). Wave-private hb -> in-order DS,
//    no barriers in the loop (single __syncthreads after weight staging).
// pre4: uint2 pre4[token][16]; lane L holds units {L, L+16 | L+32, L+48}.
// ---------------------------------------------------------------------------
__global__ __launch_bounds__(256, 4)
void prep_mfma(const float* __restrict__ x,
               const float* __restrict__ W1, const float* __restrict__ b1,
               const float* __restrict__ ln_g, const float* __restrict__ ln_b,
               const float* __restrict__ Wi, const float* __restrict__ bi,
               const float* __restrict__ Wc1, const float* __restrict__ bc1,
               uint2* __restrict__ pre4, float* __restrict__ bx)
{
    __shared__ unsigned short hb[4][16 * 88];  // h transpose, per wave
    __shared__ unsigned short wcs[64 * 72];    // Wc1[:,4:68] bf16, stride 72

    const int tid = threadIdx.x;
    const int wave = tid >> 6;
    const int lane = tid & 63;
    const int c = lane & 15;
    const int q = lane >> 4;

    const long tokW = ((long)blockIdx.x * 4 + wave) * 64;

    // tile-0 A-fragment prefetch: issue before weight staging so the first
    // vmcnt wait overlaps all of the setup below.
    const float* xp = x + (tokW + c) * DIN + q * 8;
    float4 xf0 = *(const float4*)(xp + 0);
    float4 xf1 = *(const float4*)(xp + 4);
    float4 xf2 = *(const float4*)(xp + 32);
    float4 xf3 = *(const float4*)(xp + 36);
    xp += 16 * DIN;

    // stage Wc1[:,4:68] -> LDS bf16 (block-cooperative, one barrier total)
    {
        const int row = tid >> 2, chn = tid & 3;
        const float4* s4 = (const float4*)(Wc1 + row * 68 + 4 + chn * 16);
        float4 f0 = s4[0], f1 = s4[1], f2 = s4[2], f3 = s4[3];
        uint2* dst = (uint2*)(wcs + row * 72 + chn * 16);
        dst[0] = make_uint2(cvt_pk(f0.x, f0.y), cvt_pk(f0.z, f0.w));
        dst[1] = make_uint2(cvt_pk(f1.x, f1.y), cvt_pk(f1.z, f1.w));
        dst[2] = make_uint2(cvt_pk(f2.x, f2.y), cvt_pk(f2.z, f2.w));
        dst[3] = make_uint2(cvt_pk(f3.x, f3.y), cvt_pk(f3.z, f3.w));
    }
    __syncthreads();

    // GEMM1 B-fragments: col c <- W1 row (4c+n)  [permuted: contiguous h]
    s8v W1f[4][2], Wif[2];
#pragma unroll
    for (int n = 0; n < 4; ++n)
#pragma unroll
        for (int kh = 0; kh < 2; ++kh)
            W1f[n][kh] = cvt8(W1 + (4 * c + n) * DIN + q * 8 + kh * 32);
#pragma unroll
    for (int kh = 0; kh < 2; ++kh) {
        if (c < 4) {
            Wif[kh] = cvt8(Wi + c * HH + q * 8 + kh * 32);
        } else {
            s8v z;
#pragma unroll
            for (int e = 0; e < 8; ++e) z[e] = 0;
            Wif[kh] = z;
        }
    }

    float gln[4], bln[4], b1v[4], bc1v[4];
#pragma unroll
    for (int n = 0; n < 4; ++n) {
        const int j1 = 4 * c + n;      // GEMM1 output unit for acc[n]
        const int j2 = c + 16 * n;     // GEMM2 output unit for p[n]
        gln[n] = ln_g[j1]; bln[n] = ln_b[j1]; b1v[n] = b1[j1];
        bc1v[n] = bc1[j2];
    }
    const float biv = (c < 4) ? bi[c] : 0.0f;

    unsigned short* Hb = hb[wave];
    uint2* pq = pre4 + (tokW + q * 4) * 16 + c;
    float* bq = bx + (tokW + q * 4) * SD4 + c;

    // GEMM1 + LN + GELU for one tile: pure VALU/DPP/MFMA, no DS ops.
    auto gemm1_ln = [&](s8v A0_, s8v A1_, uint2* hwo) {
        f4v acc[4];
#pragma unroll
        for (int n = 0; n < 4; ++n) {
            f4v z = { b1v[n], b1v[n], b1v[n], b1v[n] };   // bias via C-in
            z = MFMA_BF16(A0_, W1f[n][0], z);
            acc[n] = MFMA_BF16(A1_, W1f[n][1], z);
        }
        // LN stats (sum over all 64 units = 4 local + 16-lane row_ror chain)
        float sm[4], sq[4];
#pragma unroll
        for (int r = 0; r < 4; ++r) {
            sm[r] = acc[0][r] + acc[1][r] + acc[2][r] + acc[3][r];
            sq[r] = fmaf(acc[0][r], acc[0][r],
                    fmaf(acc[1][r], acc[1][r],
                    fmaf(acc[2][r], acc[2][r], acc[3][r] * acc[3][r])));
        }
#pragma unroll
        for (int r = 0; r < 4; ++r) { sm[r] += dppf<0x121>(sm[r]); sq[r] += dppf<0x121>(sq[r]); }
#pragma unroll
        for (int r = 0; r < 4; ++r) { sm[r] += dppf<0x122>(sm[r]); sq[r] += dppf<0x122>(sq[r]); }
#pragma unroll
        for (int r = 0; r < 4; ++r) { sm[r] += dppf<0x124>(sm[r]); sq[r] += dppf<0x124>(sq[r]); }
#pragma unroll
        for (int r = 0; r < 4; ++r) { sm[r] += dppf<0x128>(sm[r]); sq[r] += dppf<0x128>(sq[r]); }
#pragma unroll
        for (int r = 0; r < 4; ++r) {
            const float mu = sm[r] * (1.0f / HH);
            const float var = fmaf(-mu, mu, sq[r] * (1.0f / HH));
            const float rstd = rsqrtf(var + 1e-5f);
            float g0 = gelu_fast(fmaf((acc[0][r] - mu) * rstd, gln[0], bln[0]));
            float g1 = gelu_fast(fmaf((acc[1][r] - mu) * rstd, gln[1], bln[1]));
            float g2 = gelu_fast(fmaf((acc[2][r] - mu) * rstd, gln[2], bln[2]));
            float g3 = gelu_fast(fmaf((acc[3][r] - mu) * rstd, gln[3], bln[3]));
            hwo[r] = make_uint2(cvt_pk(g0, g1), cvt_pk(g2, g3));
        }
    };

    // ---- prologue: tile 0 through GEMM1, h(0) into hb ----
    s8v A0, A1;
    {
        union { s8v s; unsigned int u[4]; } a;
        a.u[0] = cvt_pk(xf0.x, xf0.y); a.u[1] = cvt_pk(xf0.z, xf0.w);
        a.u[2] = cvt_pk(xf1.x, xf1.y); a.u[3] = cvt_pk(xf1.z, xf1.w);
        A0 = a.s;
        a.u[0] = cvt_pk(xf2.x, xf2.y); a.u[1] = cvt_pk(xf2.z, xf2.w);
        a.u[2] = cvt_pk(xf3.x, xf3.y); a.u[3] = cvt_pk(xf3.z, xf3.w);
        A1 = a.s;
    }
    // prefetch tile-1 fragments (hidden under GEMM1(0))
    xf0 = *(const float4*)(xp + 0);
    xf1 = *(const float4*)(xp + 4);
    xf2 = *(const float4*)(xp + 32);
    xf3 = *(const float4*)(xp + 36);
    xp += 16 * DIN;

    uint2 hw[4];
    gemm1_ln(A0, A1, hw);
#pragma unroll
    for (int r = 0; r < 4; ++r) *(uint2*)(Hb + (q * 4 + r) * 88 + 4 * c) = hw[r];

    // ---- pipelined main loop ----
#pragma unroll 1
    for (int t = 0; t < 4; ++t) {
        // issue H(t) reads first; GEMM1(t+1) below has no DS ops, so their
        // lgkm latency hides under ~500 cyc of VALU before GEMM2 uses them.
        s8v H0 = *(const s8v*)(Hb + c * 88 + q * 8);
        s8v H1 = *(const s8v*)(Hb + c * 88 + 32 + q * 8);

        uint2 hwn[4];
        if (t < 3) {
            union { s8v s; unsigned int u[4]; } a;
            a.u[0] = cvt_pk(xf0.x, xf0.y); a.u[1] = cvt_pk(xf0.z, xf0.w);
            a.u[2] = cvt_pk(xf1.x, xf1.y); a.u[3] = cvt_pk(xf1.z, xf1.w);
            s8v nA0 = a.s;
            a.u[0] = cvt_pk(xf2.x, xf2.y); a.u[1] = cvt_pk(xf2.z, xf2.w);
            a.u[2] = cvt_pk(xf3.x, xf3.y); a.u[3] = cvt_pk(xf3.z, xf3.w);
            s8v nA1 = a.s;
            if (t < 2) {  // prefetch tile t+2
                xf0 = *(const float4*)(xp + 0);
                xf1 = *(const float4*)(xp + 4);
                xf2 = *(const float4*)(xp + 32);
                xf3 = *(const float4*)(xp + 36);
                xp += 16 * DIN;
            }
            gemm1_ln(nA0, nA1, hwn);
        }

        // GEMM2 (tile t): Wc1 fragments from shared LDS (stride-72 rows)
        f4v p[4];
#pragma unroll
        for (int n = 0; n < 4; ++n) {
            const s8v Wf0 = *(const s8v*)(wcs + (c + 16 * n) * 72 + q * 8);
            const s8v Wf1 = *(const s8v*)(wcs + (c + 16 * n) * 72 + 32 + q * 8);
            f4v z = { bc1v[n], bc1v[n], bc1v[n], bc1v[n] };   // bias via C-in
            z = MFMA_BF16(H0, Wf0, z);
            p[n] = MFMA_BF16(H1, Wf1, z);
        }
        f4v bz = { biv, biv, biv, biv };
        bz = MFMA_BF16(H0, Wif[0], bz);
        bz = MFMA_BF16(H1, Wif[1], bz);

        if (c < 4) {
#pragma unroll
            for (int r = 0; r < 4; ++r) bq[r * SD4] = bz[r];
        }
#pragma unroll
        for (int r = 0; r < 4; ++r)
            pq[r * 16] = make_uint2(cvt_pk(p[0][r], p[1][r]),
                                    cvt_pk(p[2][r], p[3][r]));
        pq += 256; bq += 64;

        // h(t+1) -> hb AFTER the H(t)/Wf reads (per-wave in-order DS => safe)
        if (t < 3) {
#pragma unroll
            for (int r = 0; r < 4; ++r) *(uint2*)(Hb + (q * 4 + r) * 88 + 4 * c) = hwn[r];
        }
    }
}

// ---------------------------------------------------------------------------
// Phase 2: chunked-parallel scan. Task = (batch, chunk of CH=64); warm-up
// <= LB=64 steps from s=0. 8192 tasks x 16 lanes -> 2048 waves -> 2 waves/SIMD
// (issue-bound: 2x575 issue-cyc/step > 890 chain-cyc/step). Lane L owns units
// j = L+16m. Cross-lane via DPP only. ci block-uniform.
// ---------------------------------------------------------------------------
__global__ __launch_bounds__(256)
void scan_chunk(const uint2* __restrict__ pre4, const float* __restrict__ bx,
                const float* __restrict__ Wc1, const float* __restrict__ Wc2,
                const float* __restrict__ bc2, const float* __restrict__ corr_scale,
                const float* __restrict__ A_level, const float* __restrict__ A_trend,
                const float* __restrict__ A_gamma, const float* __restrict__ A_resid,
                const float* __restrict__ omega, float* __restrict__ out)
{
    const int tid = threadIdx.x;
    const int task = blockIdx.x * 16 + (tid >> 4);
    const int L = tid & 15;
    const int ci = task >> 9;        // block-uniform (16 contiguous tasks/block)
    const int b = task & 511;
    const int warm = (ci * CH < LB) ? ci * CH : LB;
    const int t0 = ci * CH - warm;
    const int nsteps = warm + CH;    // 64 or 128

    float w[4][4], v[4][4];
#pragma unroll
    for (int m = 0; m < 4; ++m) {
        const int j = L + 16 * m;
#pragma unroll
        for (int k = 0; k < 4; ++k) {
            w[m][k] = Wc1[j * 68 + k];
            v[k][m] = Wc2[k * HH + j];
        }
    }
    const float cs = corr_scale[0];
    const float a0 = sigmoid_f(A_level[0]) * 0.15f + 0.85f;
    const float a1 = sigmoid_f(A_trend[0]) * 0.25f + 0.70f;
    const float a2 = (sigmoid_f(A_gamma[0]) * 0.2f + 0.8f) * cosf(omega[0]);
    const float a3 = sigmoid_f(A_resid[0]) * 0.4f;
    const float csel = bc2[L & 3];
    const bool o1 = (L & 1) != 0;
    const bool o2 = (L & 2) != 0;

    const uint2* pp = pre4 + ((long)b * SS + t0) * 16 + L;
    const float4* bp = (const float4*)bx + (long)b * SS + t0;
    float* op = out + ((long)b * SS + t0) * SD4;

    float s0 = 0.f, s1 = 0.f, s2 = 0.f, s3 = 0.f;

    uint2 pv[4]; float4 bv[4];
#pragma unroll
    for (int i = 0; i < 4; ++i) { pv[i] = pp[(long)i * 16]; bv[i] = bp[i]; }

#pragma unroll 2
    for (int tt = 0; tt < nsteps; tt += 4) {
        // wave-uniform clamped prefetch base
        const int ntt = (tt + 4 < nsteps) ? (tt + 4) : (nsteps - 4);
        const uint2* qp = pp + (long)ntt * 16;
        const float4* qb = bp + ntt;
        uint2 np[4]; float4 nb[4];
#pragma unroll
        for (int i = 0; i < 4; ++i) { np[i] = qp[i * 16]; nb[i] = qb[i]; }

        const bool wr = (tt >= warm);  // uniform; warm is a multiple of 4
#pragma unroll
        for (int i = 0; i < 4; ++i) {
            const float l0 = fmaf(a0, s0, bv[i].x);
            const float l1 = fmaf(a1, s1, bv[i].y);
            const float l2 = fmaf(a2, s2, bv[i].z);
            const float l3 = fmaf(a3, s3, bv[i].w);
            const float p0 = bf2f((unsigned short)(pv[i].x & 0xffffu));
            const float p1 = bf2f((unsigned short)(pv[i].x >> 16));
            const float p2 = bf2f((unsigned short)(pv[i].y & 0xffffu));
            const float p3 = bf2f((unsigned short)(pv[i].y >> 16));
            float g[4];
            {
                float ua0 = fmaf(l0, w[0][0], p0), ub0 = fmaf(l2, w[0][2], l3 * w[0][3]);
                float ua1 = fmaf(l0, w[1][0], p1), ub1 = fmaf(l2, w[1][2], l3 * w[1][3]);
                float ua2 = fmaf(l0, w[2][0], p2), ub2 = fmaf(l2, w[2][2], l3 * w[2][3]);
                float ua3 = fmaf(l0, w[3][0], p3), ub3 = fmaf(l2, w[3][2], l3 * w[3][3]);
                g[0] = gelu_fast(fmaf(l1, w[0][1], ua0) + ub0);
                g[1] = gelu_fast(fmaf(l1, w[1][1], ua1) + ub1);
                g[2] = gelu_fast(fmaf(l1, w[2][1], ua2) + ub2);
                g[3] = gelu_fast(fmaf(l1, w[3][1], ua3) + ub3);
            }
            const float P0 = fmaf(g[0], v[0][0], g[1] * v[0][1]) + fmaf(g[2], v[0][2], g[3] * v[0][3]);
            const float P1 = fmaf(g[0], v[1][0], g[1] * v[1][1]) + fmaf(g[2], v[1][2], g[3] * v[1][3]);
            const float P2 = fmaf(g[0], v[2][0], g[1] * v[2][1]) + fmaf(g[2], v[2][2], g[3] * v[2][3]);
            const float P3 = fmaf(g[0], v[3][0], g[1] * v[3][1]) + fmaf(g[2], v[3][2], g[3] * v[3][3]);
            const float k0 = o1 ? P1 : P0, s0s = o1 ? P0 : P1;
            const float k1 = o1 ? P3 : P2, s1s = o1 ? P2 : P3;
            const float Af = k0 + dppf<0xB1>(s0s);   // quad_perm xor 1
            const float Bf = k1 + dppf<0xB1>(s1s);
            const float kk = o2 ? Bf : Af, ss = o2 ? Af : Bf;
            float T = kk + dppf<0x4E>(ss);           // quad_perm xor 2
            T += dppf<0x124>(T);                     // row_ror:4
            T += dppf<0x128>(T);                     // row_ror:8
            const float th = tanh_fast(T + csel);
            const float lsel = o2 ? (o1 ? l3 : l2) : (o1 ? l1 : l0);
            const float sval = fmaf(cs, th, lsel);
            s0 = dppf<0x00>(sval);
            s1 = dppf<0x55>(sval);
            s2 = dppf<0xAA>(sval);
            s3 = dppf<0xFF>(sval);
            if (wr && L < 4) op[(tt + i) * SD4 + L] = sval;
        }
#pragma unroll
        for (int i = 0; i < 4; ++i) { pv[i] = np[i]; bv[i] = nb[i]; }
    }
}

extern "C" void kernel_launch(void* const* d_in, const int* in_sizes, int n_in,
                              void* d_out, int out_size, void* d_ws, size_t ws_size,
                              hipStream_t stream) {
    (void)in_sizes; (void)n_in; (void)out_size; (void)ws_size;
    const float* x    = (const float*)d_in[0];
    const float* W1   = (const float*)d_in[1];
    const float* b1   = (const float*)d_in[2];
    const float* ln_g = (const float*)d_in[3];
    const float* ln_b = (const float*)d_in[4];
    const float* Wi   = (const float*)d_in[5];
    const float* bi   = (const float*)d_in[6];
    const float* Wc1  = (const float*)d_in[7];
    const float* bc1  = (const float*)d_in[8];
    const float* Wc2  = (const float*)d_in[9];
    const float* bc2  = (const float*)d_in[10];
    const float* corr = (const float*)d_in[11];
    const float* Al   = (const float*)d_in[12];
    const float* At   = (const float*)d_in[13];
    const float* Ag   = (const float*)d_in[14];
    const float* Ar   = (const float*)d_in[15];
    const float* om   = (const float*)d_in[16];

    uint2* pre4 = (uint2*)d_ws;  // 512*1024*16 uint2 = 64 MiB
    float* bx = (float*)((char*)d_ws + (size_t)BB * SS * 16 * sizeof(uint2)); // 8 MiB
    float* out = (float*)d_out;

    prep_mfma<<<dim3(2048), dim3(256), 0, stream>>>(
        x, W1, b1, ln_g, ln_b, Wi, bi, Wc1, bc1, pre4, bx);
    scan_chunk<<<dim3(BB * SS / CH / 16), dim3(256), 0, stream>>>(
        pre4, bx, Wc1, Wc2, bc2, corr, Al, At, Ag, Ar, om, out);
}

// Round 2
// 298.240 us; speedup vs baseline: 1.0855x; 1.0855x over previous
//
#include <hip/hip_runtime.h>
#include <hip/hip_bf16.h>

#define BB 512
#define SS 1024
#define DIN 64
#define HH 64
#define SD4 4
#define CH 64     // scan chunk length
#define LB 64     // scan lookback (0.925^64 = 6.8e-3 decay of init error)

typedef __attribute__((ext_vector_type(8))) short s8v;   // 8 bf16 (4 VGPRs)
typedef __attribute__((ext_vector_type(4))) float f4v;   // MFMA accumulator

#define MFMA_BF16(a, b, c) __builtin_amdgcn_mfma_f32_16x16x32_bf16((a), (b), (c), 0, 0, 0)

// DPP cross-lane move in the VALU pipe. ctrl: 0x00-0xFF quad_perm; 0x120+N row_ror:N.
template <int CTRL>
__device__ __forceinline__ float dppf(float v) {
    return __int_as_float(__builtin_amdgcn_mov_dpp(__float_as_int(v), CTRL, 0xF, 0xF, false));
}

__device__ __forceinline__ float rcp_fast(float x) {
    return __builtin_amdgcn_rcpf(x);   // v_rcp_f32: 1 instr, ~1 ulp
}
// HW packed f32->bf16 (RNE), 2 elements per instruction.
__device__ __forceinline__ unsigned int cvt_pk(float lo, float hi) {
    unsigned int r;
    asm("v_cvt_pk_bf16_f32 %0, %1, %2" : "=v"(r) : "v"(lo), "v"(hi));
    return r;
}
__device__ __forceinline__ float bf2f(unsigned short u) {
    return __uint_as_float(((unsigned int)u) << 16);
}
__device__ __forceinline__ float sigmoid_f(float x) {
    return 1.0f / (1.0f + __expf(-x));
}
__device__ __forceinline__ float tanh_fast(float x) {
    return fmaf(-2.0f, rcp_fast(__expf(2.0f * x) + 1.0f), 1.0f);
}
__device__ __forceinline__ float gelu_fast(float x) {
    // tanh-form GELU as x*sigmoid(-z)
    float x2 = x * x;
    float z = x * fmaf(x2, -0.0713548162f, -1.5957691216f);
    return x * rcp_fast(1.0f + __expf(z));
}
__device__ __forceinline__ s8v cvt8(const float* __restrict__ p) {
    const float4* q4 = (const float4*)p;
    float4 a = q4[0], b = q4[1];
    union { s8v s; unsigned int u[4]; } r;
    r.u[0] = cvt_pk(a.x, a.y); r.u[1] = cvt_pk(a.z, a.w);
    r.u[2] = cvt_pk(b.x, b.y); r.u[3] = cvt_pk(b.z, b.w);
    return r.s;
}

// ---------------------------------------------------------------------------
// Phase 1 (MFMA), per 16-token tile:
//   h = GELU(LN(x @ W1^T + b1)); pre = h @ Wc1[:,4:]^T + bc1; bx = h @ Wi^T + bi
// R7 = R6 structure, regalloc unconstrained (NO waves-per-EU hint: R6's
// __launch_bounds__(256,4) forced VGPR=64 -> ~131 MB of scratch spill traffic,
// dur 81->109us. Live set needs ~110-130 VGPRs).
//  - A-fragments loaded DIRECTLY from global (lane (c,q) owns x[tok0+c][q*8..])
//    one tile ahead; no xs LDS stage, conversions via v_cvt_pk_bf16_f32.
//  - Biases folded into MFMA C-in.
//  - Wc1 B-fragments live in block-shared LDS (bf16, row stride 72 shorts ->
//    bank-floor reads), freeing 32 persistent VGPRs.
//  - Software pipeline: iter t issues H(t) ds_reads, then runs GEMM1(t+1)+LN+
//    GELU (pure VALU, no DS ops) to hide the hb round-trip, then GEMM2(t),
//    stores(t), and finally ds_writes h(t+1). Wave-private hb -> in-order DS,
//    no barriers in the loop (single __syncthreads after weight staging).
// pre4: uint2 pre4[token][16]; lane L holds units {L, L+16 | L+32, L+48}.
// ---------------------------------------------------------------------------
__global__ __launch_bounds__(256)
void prep_mfma(const float* __restrict__ x,
               const float* __restrict__ W1, const float* __restrict__ b1,
               const float* __restrict__ ln_g, const float* __restrict__ ln_b,
               const float* __restrict__ Wi, const float* __restrict__ bi,
               const float* __restrict__ Wc1, const float* __restrict__ bc1,
               uint2* __restrict__ pre4, float* __restrict__ bx)
{
    __shared__ unsigned short hb[4][16 * 88];  // h transpose, per wave
    __shared__ unsigned short wcs[64 * 72];    // Wc1[:,4:68] bf16, stride 72

    const int tid = threadIdx.x;
    const int wave = tid >> 6;
    const int lane = tid & 63;
    const int c = lane & 15;
    const int q = lane >> 4;

    const long tokW = ((long)blockIdx.x * 4 + wave) * 64;

    // tile-0 A-fragment prefetch: issue before weight staging so the first
    // vmcnt wait overlaps all of the setup below.
    const float* xp = x + (tokW + c) * DIN + q * 8;
    float4 xf0 = *(const float4*)(xp + 0);
    float4 xf1 = *(const float4*)(xp + 4);
    float4 xf2 = *(const float4*)(xp + 32);
    float4 xf3 = *(const float4*)(xp + 36);
    xp += 16 * DIN;

    // stage Wc1[:,4:68] -> LDS bf16 (block-cooperative, one barrier total)
    {
        const int row = tid >> 2, chn = tid & 3;
        const float4* s4 = (const float4*)(Wc1 + row * 68 + 4 + chn * 16);
        float4 f0 = s4[0], f1 = s4[1], f2 = s4[2], f3 = s4[3];
        uint2* dst = (uint2*)(wcs + row * 72 + chn * 16);
        dst[0] = make_uint2(cvt_pk(f0.x, f0.y), cvt_pk(f0.z, f0.w));
        dst[1] = make_uint2(cvt_pk(f1.x, f1.y), cvt_pk(f1.z, f1.w));
        dst[2] = make_uint2(cvt_pk(f2.x, f2.y), cvt_pk(f2.z, f2.w));
        dst[3] = make_uint2(cvt_pk(f3.x, f3.y), cvt_pk(f3.z, f3.w));
    }
    __syncthreads();

    // GEMM1 B-fragments: col c <- W1 row (4c+n)  [permuted: contiguous h]
    s8v W1f[4][2], Wif[2];
#pragma unroll
    for (int n = 0; n < 4; ++n)
#pragma unroll
        for (int kh = 0; kh < 2; ++kh)
            W1f[n][kh] = cvt8(W1 + (4 * c + n) * DIN + q * 8 + kh * 32);
#pragma unroll
    for (int kh = 0; kh < 2; ++kh) {
        if (c < 4) {
            Wif[kh] = cvt8(Wi + c * HH + q * 8 + kh * 32);
        } else {
            s8v z;
#pragma unroll
            for (int e = 0; e < 8; ++e) z[e] = 0;
            Wif[kh] = z;
        }
    }

    float gln[4], bln[4], b1v[4], bc1v[4];
#pragma unroll
    for (int n = 0; n < 4; ++n) {
        const int j1 = 4 * c + n;      // GEMM1 output unit for acc[n]
        const int j2 = c + 16 * n;     // GEMM2 output unit for p[n]
        gln[n] = ln_g[j1]; bln[n] = ln_b[j1]; b1v[n] = b1[j1];
        bc1v[n] = bc1[j2];
    }
    const float biv = (c < 4) ? bi[c] : 0.0f;

    unsigned short* Hb = hb[wave];
    uint2* pq = pre4 + (tokW + q * 4) * 16 + c;
    float* bq = bx + (tokW + q * 4) * SD4 + c;

    // GEMM1 + LN + GELU for one tile: pure VALU/DPP/MFMA, no DS ops.
    auto gemm1_ln = [&](s8v A0_, s8v A1_, uint2* hwo) {
        f4v acc[4];
#pragma unroll
        for (int n = 0; n < 4; ++n) {
            f4v z = { b1v[n], b1v[n], b1v[n], b1v[n] };   // bias via C-in
            z = MFMA_BF16(A0_, W1f[n][0], z);
            acc[n] = MFMA_BF16(A1_, W1f[n][1], z);
        }
        // LN stats (sum over all 64 units = 4 local + 16-lane row_ror chain)
        float sm[4], sq[4];
#pragma unroll
        for (int r = 0; r < 4; ++r) {
            sm[r] = acc[0][r] + acc[1][r] + acc[2][r] + acc[3][r];
            sq[r] = fmaf(acc[0][r], acc[0][r],
                    fmaf(acc[1][r], acc[1][r],
                    fmaf(acc[2][r], acc[2][r], acc[3][r] * acc[3][r])));
        }
#pragma unroll
        for (int r = 0; r < 4; ++r) { sm[r] += dppf<0x121>(sm[r]); sq[r] += dppf<0x121>(sq[r]); }
#pragma unroll
        for (int r = 0; r < 4; ++r) { sm[r] += dppf<0x122>(sm[r]); sq[r] += dppf<0x122>(sq[r]); }
#pragma unroll
        for (int r = 0; r < 4; ++r) { sm[r] += dppf<0x124>(sm[r]); sq[r] += dppf<0x124>(sq[r]); }
#pragma unroll
        for (int r = 0; r < 4; ++r) { sm[r] += dppf<0x128>(sm[r]); sq[r] += dppf<0x128>(sq[r]); }
#pragma unroll
        for (int r = 0; r < 4; ++r) {
            const float mu = sm[r] * (1.0f / HH);
            const float var = fmaf(-mu, mu, sq[r] * (1.0f / HH));
            const float rstd = rsqrtf(var + 1e-5f);
            float g0 = gelu_fast(fmaf((acc[0][r] - mu) * rstd, gln[0], bln[0]));
            float g1 = gelu_fast(fmaf((acc[1][r] - mu) * rstd, gln[1], bln[1]));
            float g2 = gelu_fast(fmaf((acc[2][r] - mu) * rstd, gln[2], bln[2]));
            float g3 = gelu_fast(fmaf((acc[3][r] - mu) * rstd, gln[3], bln[3]));
            hwo[r] = make_uint2(cvt_pk(g0, g1), cvt_pk(g2, g3));
        }
    };

    // ---- prologue: tile 0 through GEMM1, h(0) into hb ----
    s8v A0, A1;
    {
        union { s8v s; unsigned int u[4]; } a;
        a.u[0] = cvt_pk(xf0.x, xf0.y); a.u[1] = cvt_pk(xf0.z, xf0.w);
        a.u[2] = cvt_pk(xf1.x, xf1.y); a.u[3] = cvt_pk(xf1.z, xf1.w);
        A0 = a.s;
        a.u[0] = cvt_pk(xf2.x, xf2.y); a.u[1] = cvt_pk(xf2.z, xf2.w);
        a.u[2] = cvt_pk(xf3.x, xf3.y); a.u[3] = cvt_pk(xf3.z, xf3.w);
        A1 = a.s;
    }
    // prefetch tile-1 fragments (hidden under GEMM1(0))
    xf0 = *(const float4*)(xp + 0);
    xf1 = *(const float4*)(xp + 4);
    xf2 = *(const float4*)(xp + 32);
    xf3 = *(const float4*)(xp + 36);
    xp += 16 * DIN;

    uint2 hw[4];
    gemm1_ln(A0, A1, hw);
#pragma unroll
    for (int r = 0; r < 4; ++r) *(uint2*)(Hb + (q * 4 + r) * 88 + 4 * c) = hw[r];

    // ---- pipelined main loop ----
#pragma unroll 1
    for (int t = 0; t < 4; ++t) {
        // issue H(t) reads first; GEMM1(t+1) below has no DS ops, so their
        // lgkm latency hides under ~500 cyc of VALU before GEMM2 uses them.
        s8v H0 = *(const s8v*)(Hb + c * 88 + q * 8);
        s8v H1 = *(const s8v*)(Hb + c * 88 + 32 + q * 8);

        uint2 hwn[4];
        if (t < 3) {
            union { s8v s; unsigned int u[4]; } a;
            a.u[0] = cvt_pk(xf0.x, xf0.y); a.u[1] = cvt_pk(xf0.z, xf0.w);
            a.u[2] = cvt_pk(xf1.x, xf1.y); a.u[3] = cvt_pk(xf1.z, xf1.w);
            s8v nA0 = a.s;
            a.u[0] = cvt_pk(xf2.x, xf2.y); a.u[1] = cvt_pk(xf2.z, xf2.w);
            a.u[2] = cvt_pk(xf3.x, xf3.y); a.u[3] = cvt_pk(xf3.z, xf3.w);
            s8v nA1 = a.s;
            if (t < 2) {  // prefetch tile t+2
                xf0 = *(const float4*)(xp + 0);
                xf1 = *(const float4*)(xp + 4);
                xf2 = *(const float4*)(xp + 32);
                xf3 = *(const float4*)(xp + 36);
                xp += 16 * DIN;
            }
            gemm1_ln(nA0, nA1, hwn);
        }

        // GEMM2 (tile t): Wc1 fragments from shared LDS (stride-72 rows)
        f4v p[4];
#pragma unroll
        for (int n = 0; n < 4; ++n) {
            const s8v Wf0 = *(const s8v*)(wcs + (c + 16 * n) * 72 + q * 8);
            const s8v Wf1 = *(const s8v*)(wcs + (c + 16 * n) * 72 + 32 + q * 8);
            f4v z = { bc1v[n], bc1v[n], bc1v[n], bc1v[n] };   // bias via C-in
            z = MFMA_BF16(H0, Wf0, z);
            p[n] = MFMA_BF16(H1, Wf1, z);
        }
        f4v bz = { biv, biv, biv, biv };
        bz = MFMA_BF16(H0, Wif[0], bz);
        bz = MFMA_BF16(H1, Wif[1], bz);

        if (c < 4) {
#pragma unroll
            for (int r = 0; r < 4; ++r) bq[r * SD4] = bz[r];
        }
#pragma unroll
        for (int r = 0; r < 4; ++r)
            pq[r * 16] = make_uint2(cvt_pk(p[0][r], p[1][r]),
                                    cvt_pk(p[2][r], p[3][r]));
        pq += 256; bq += 64;

        // h(t+1) -> hb AFTER the H(t)/Wf reads (per-wave in-order DS => safe)
        if (t < 3) {
#pragma unroll
            for (int r = 0; r < 4; ++r) *(uint2*)(Hb + (q * 4 + r) * 88 + 4 * c) = hwn[r];
        }
    }
}

// ---------------------------------------------------------------------------
// Phase 2: chunked-parallel scan. Task = (batch, chunk of CH=64); warm-up
// <= LB=64 steps from s=0. 8192 tasks x 16 lanes -> 2048 waves -> 2 waves/SIMD
// (issue-bound: 2x575 issue-cyc/step > 890 chain-cyc/step). Lane L owns units
// j = L+16m. Cross-lane via DPP only. ci block-uniform.
// ---------------------------------------------------------------------------
__global__ __launch_bounds__(256)
void scan_chunk(const uint2* __restrict__ pre4, const float* __restrict__ bx,
                const float* __restrict__ Wc1, const float* __restrict__ Wc2,
                const float* __restrict__ bc2, const float* __restrict__ corr_scale,
                const float* __restrict__ A_level, const float* __restrict__ A_trend,
                const float* __restrict__ A_gamma, const float* __restrict__ A_resid,
                const float* __restrict__ omega, float* __restrict__ out)
{
    const int tid = threadIdx.x;
    const int task = blockIdx.x * 16 + (tid >> 4);
    const int L = tid & 15;
    const int ci = task >> 9;        // block-uniform (16 contiguous tasks/block)
    const int b = task & 511;
    const int warm = (ci * CH < LB) ? ci * CH : LB;
    const int t0 = ci * CH - warm;
    const int nsteps = warm + CH;    // 64 or 128

    float w[4][4], v[4][4];
#pragma unroll
    for (int m = 0; m < 4; ++m) {
        const int j = L + 16 * m;
#pragma unroll
        for (int k = 0; k < 4; ++k) {
            w[m][k] = Wc1[j * 68 + k];
            v[k][m] = Wc2[k * HH + j];
        }
    }
    const float cs = corr_scale[0];
    const float a0 = sigmoid_f(A_level[0]) * 0.15f + 0.85f;
    const float a1 = sigmoid_f(A_trend[0]) * 0.25f + 0.70f;
    const float a2 = (sigmoid_f(A_gamma[0]) * 0.2f + 0.8f) * cosf(omega[0]);
    const float a3 = sigmoid_f(A_resid[0]) * 0.4f;
    const float csel = bc2[L & 3];
    const bool o1 = (L & 1) != 0;
    const bool o2 = (L & 2) != 0;

    const uint2* pp = pre4 + ((long)b * SS + t0) * 16 + L;
    const float4* bp = (const float4*)bx + (long)b * SS + t0;
    float* op = out + ((long)b * SS + t0) * SD4;

    float s0 = 0.f, s1 = 0.f, s2 = 0.f, s3 = 0.f;

    uint2 pv[4]; float4 bv[4];
#pragma unroll
    for (int i = 0; i < 4; ++i) { pv[i] = pp[(long)i * 16]; bv[i] = bp[i]; }

#pragma unroll 2
    for (int tt = 0; tt < nsteps; tt += 4) {
        // wave-uniform clamped prefetch base
        const int ntt = (tt + 4 < nsteps) ? (tt + 4) : (nsteps - 4);
        const uint2* qp = pp + (long)ntt * 16;
        const float4* qb = bp + ntt;
        uint2 np[4]; float4 nb[4];
#pragma unroll
        for (int i = 0; i < 4; ++i) { np[i] = qp[i * 16]; nb[i] = qb[i]; }

        const bool wr = (tt >= warm);  // uniform; warm is a multiple of 4
#pragma unroll
        for (int i = 0; i < 4; ++i) {
            const float l0 = fmaf(a0, s0, bv[i].x);
            const float l1 = fmaf(a1, s1, bv[i].y);
            const float l2 = fmaf(a2, s2, bv[i].z);
            const float l3 = fmaf(a3, s3, bv[i].w);
            const float p0 = bf2f((unsigned short)(pv[i].x & 0xffffu));
            const float p1 = bf2f((unsigned short)(pv[i].x >> 16));
            const float p2 = bf2f((unsigned short)(pv[i].y & 0xffffu));
            const float p3 = bf2f((unsigned short)(pv[i].y >> 16));
            float g[4];
            {
                float ua0 = fmaf(l0, w[0][0], p0), ub0 = fmaf(l2, w[0][2], l3 * w[0][3]);
                float ua1 = fmaf(l0, w[1][0], p1), ub1 = fmaf(l2, w[1][2], l3 * w[1][3]);
                float ua2 = fmaf(l0, w[2][0], p2), ub2 = fmaf(l2, w[2][2], l3 * w[2][3]);
                float ua3 = fmaf(l0, w[3][0], p3), ub3 = fmaf(l2, w[3][2], l3 * w[3][3]);
                g[0] = gelu_fast(fmaf(l1, w[0][1], ua0) + ub0);
                g[1] = gelu_fast(fmaf(l1, w[1][1], ua1) + ub1);
                g[2] = gelu_fast(fmaf(l1, w[2][1], ua2) + ub2);
                g[3] = gelu_fast(fmaf(l1, w[3][1], ua3) + ub3);
            }
            const float P0 = fmaf(g[0], v[0][0], g[1] * v[0][1]) + fmaf(g[2], v[0][2], g[3] * v[0][3]);
            const float P1 = fmaf(g[0], v[1][0], g[1] * v[1][1]) + fmaf(g[2], v[1][2], g[3] * v[1][3]);
            const float P2 = fmaf(g[0], v[2][0], g[1] * v[2][1]) + fmaf(g[2], v[2][2], g[3] * v[2][3]);
            const float P3 = fmaf(g[0], v[3][0], g[1] * v[3][1]) + fmaf(g[2], v[3][2], g[3] * v[3][3]);
            const float k0 = o1 ? P1 : P0, s0s = o1 ? P0 : P1;
            const float k1 = o1 ? P3 : P2, s1s = o1 ? P2 : P3;
            const float Af = k0 + dppf<0xB1>(s0s);   // quad_perm xor 1
            const float Bf = k1 + dppf<0xB1>(s1s);
            const float kk = o2 ? Bf : Af, ss = o2 ? Af : Bf;
            float T = kk + dppf<0x4E>(ss);           // quad_perm xor 2
            T += dppf<0x124>(T);                     // row_ror:4
            T += dppf<0x128>(T);                     // row_ror:8
            const float th = tanh_fast(T + csel);
            const float lsel = o2 ? (o1 ? l3 : l2) : (o1 ? l1 : l0);
            const float sval = fmaf(cs, th, lsel);
            s0 = dppf<0x00>(sval);
            s1 = dppf<0x55>(sval);
            s2 = dppf<0xAA>(sval);
            s3 = dppf<0xFF>(sval);
            if (wr && L < 4) op[(tt + i) * SD4 + L] = sval;
        }
#pragma unroll
        for (int i = 0; i < 4; ++i) { pv[i] = np[i]; bv[i] = nb[i]; }
    }
}

extern "C" void kernel_launch(void* const* d_in, const int* in_sizes, int n_in,
                              void* d_out, int out_size, void* d_ws, size_t ws_size,
                              hipStream_t stream) {
    (void)in_sizes; (void)n_in; (void)out_size; (void)ws_size;
    const float* x    = (const float*)d_in[0];
    const float* W1   = (const float*)d_in[1];
    const float* b1   = (const float*)d_in[2];
    const float* ln_g = (const float*)d_in[3];
    const float* ln_b = (const float*)d_in[4];
    const float* Wi   = (const float*)d_in[5];
    const float* bi   = (const float*)d_in[6];
    const float* Wc1  = (const float*)d_in[7];
    const float* bc1  = (const float*)d_in[8];
    const float* Wc2  = (const float*)d_in[9];
    const float* bc2  = (const float*)d_in[10];
    const float* corr = (const float*)d_in[11];
    const float* Al   = (const float*)d_in[12];
    const float* At   = (const float*)d_in[13];
    const float* Ag   = (const float*)d_in[14];
    const float* Ar   = (const float*)d_in[15];
    const float* om   = (const float*)d_in[16];

    uint2* pre4 = (uint2*)d_ws;  // 512*1024*16 uint2 = 64 MiB
    float* bx = (float*)((char*)d_ws + (size_t)BB * SS * 16 * sizeof(uint2)); // 8 MiB
    float* out = (float*)d_out;

    prep_mfma<<<dim3(2048), dim3(256), 0, stream>>>(
        x, W1, b1, ln_g, ln_b, Wi, bi, Wc1, bc1, pre4, bx);
    scan_chunk<<<dim3(BB * SS / CH / 16), dim3(256), 0, stream>>>(
        pre4, bx, Wc1, Wc2, bc2, corr, Al, At, Ag, Ar, om, out);
}